// Round 11
// baseline (354.438 us; speedup 1.0000x reference)
//
#include <hip/hip_runtime.h>
#include <hip/hip_bf16.h>
#include <stdint.h>

// ---------- types / helpers ----------
typedef __bf16 bf16x8_t __attribute__((ext_vector_type(8)));
typedef float f32x4_t __attribute__((ext_vector_type(4)));
typedef unsigned short ushort8_t __attribute__((ext_vector_type(8)));  // 16B aligned

__device__ __forceinline__ unsigned short f2bf(float f) {
    union { float f; uint32_t i; } v; v.f = f;
    uint32_t i = v.i + (((v.i >> 16) & 1u) + 0x7FFFu);   // RNE
    return (unsigned short)(i >> 16);
}

typedef const __attribute__((address_space(1))) void* gas_t;
typedef __attribute__((address_space(3))) void* las_t;
__device__ __forceinline__ void load_lds16(const unsigned short* g, unsigned short* l) {
    // async global->LDS DMA; LDS dest = wave-uniform base + lane*16B
    __builtin_amdgcn_global_load_lds((gas_t)g, (las_t)l, 16, 0, 0);
}

// ---------- problem constants ----------
#define BB   256
#define CC   3
#define HH   128
#define WW   128
#define PP   768        // C*K*K
#define HID  2048
#define LL   256
#define MM   16384      // B*GH*GW

// ---------- patchify: x f32 (B,C,H,W) -> patches bf16 (M,768), u16-view of out0 ----------
__global__ void patchify(const float* __restrict__ x,
                         unsigned short* __restrict__ patches) {
    int t = blockIdx.x * 256 + threadIdx.x;        // 1,572,864 threads, 8 elems each
    int e = t * 8;                                  // linear index into x
    int col = e & 127;                              // w (multiple of 8)
    int row = (e >> 7) & 127;                       // h
    int c   = (e >> 14) % 3;
    int b   = e / (128 * 128 * 3);
    int gh = row >> 4, kh = row & 15, gw = col >> 4, kw = col & 15;
    long po = (long)(b * 64 + gh * 8 + gw) * PP + c * 256 + kh * 16 + kw;
    float4 v0 = *(const float4*)(x + e);
    float4 v1 = *(const float4*)(x + e + 4);
    ushort8_t o;
    o[0] = f2bf(v0.x); o[1] = f2bf(v0.y); o[2] = f2bf(v0.z); o[3] = f2bf(v0.w);
    o[4] = f2bf(v1.x); o[5] = f2bf(v1.y); o[6] = f2bf(v1.z); o[7] = f2bf(v1.w);
    *(ushort8_t*)(patches + po) = o;
}

// ---------- 32x32-tiled transpose + cast: out bf16[c*R+r] = in f32[r*C+c] ----------
__global__ void transpose_k(const float* __restrict__ in,
                            unsigned short* __restrict__ out, int R, int C) {
    __shared__ unsigned short tile[32][34];
    int nbc = C >> 5;
    int tc = blockIdx.x % nbc, tr = blockIdx.x / nbc;
    int tx = threadIdx.x & 31, ty0 = threadIdx.x >> 5;   // 8 rows/pass
    int r0 = tr << 5, c0 = tc << 5;
    #pragma unroll
    for (int i = 0; i < 4; ++i) {
        int ty = ty0 + i * 8;
        tile[ty][tx] = f2bf(in[(long)(r0 + ty) * C + c0 + tx]);
    }
    __syncthreads();
    #pragma unroll
    for (int i = 0; i < 4; ++i) {
        int ty = ty0 + i * 8;
        out[(long)(c0 + ty) * R + r0 + tx] = tile[tx][ty];
    }
}

// ---------- GEMM: C(rows x N) = act(A(rows x K) @ Bt(N x K)^T + bias f32) ----------
// R5 structure (best measured): tile 256x128, BK=32, 8 waves 4x2, per-wave
// 64x64. TRIPLE-buffered LDS (72 KiB) -> 2 blocks/CU. Counted vmcnt(3).
// NOTE (R6/R7): 4-phase barrier schedules + 256x256 tile REGRESSED.
// NOTE (R9): additive model CONFIRMED (G2->128sq cut total 373->349, -24us).
//   Chain work translates 1:1. G4 (384 blocks = 1.5/CU, imbalanced) is this
//   round's target -> 128sq variant, 768 blocks = exactly 3/CU.
// LDS swizzle: flat 16B-group involution G' = G ^ ((G>>3)&7) (rule #21).
// ACT: 0=none 1=relu 2=sigmoid.  WMODE as before.
#define BMT 256
#define BNT 128
#define BKT 32
#define LDS_TILE ((BMT + BNT) * BKT)   // 12288 elems = 24 KiB per buffer

template <int ACT, int WMODE>
__global__ void __launch_bounds__(512, 4)
gemm_bt(const unsigned short* __restrict__ A, int lda,
        const unsigned short* __restrict__ Bt,
        const float* __restrict__ bias,
        unsigned short* __restrict__ C0u,
        float* __restrict__ C0f,
        float* __restrict__ C1f,
        int ldc, int Kd, int nbn, int m0) {
    __shared__ __align__(16) unsigned short lds_buf[3 * LDS_TILE];   // 72 KiB
    const int nbm = gridDim.x / nbn;
    const int stripe = nbm >> 3;                 // bm rows per XCD
    const int xcd = blockIdx.x & 7;
    const int loc = blockIdx.x >> 3;
    const int bm = xcd * stripe + (loc % stripe);
    const int bn = loc / stripe;
    const int tid = threadIdx.x;
    const int wave = tid >> 6;
    const int lane = tid & 63;
    const int wr = wave >> 1;                    // 0..3 (M)
    const int wc = wave & 1;                     // 0..1 (N)
    const int fr = lane & 15;
    const int quad = lane >> 4;

    const int Gl = tid ^ ((tid >> 3) & 7);
    const int sr = Gl >> 2;                      // logical row 0..127
    const int sg = (Gl & 3) << 3;                // logical col elem 0/8/16/24

    const unsigned short* Ab = A + (long)bm * BMT * lda;
    const unsigned short* Bb = Bt + (long)bn * BNT * Kd;

    int gA[4], gB[4];
    #pragma unroll
    for (int i = 0; i < 4; ++i) {
        const int r = (wr << 6) + (i << 4) + fr;
        gA[i] = ((((r << 2) | quad) ^ ((r >> 1) & 7)) << 3);
    }
    #pragma unroll
    for (int j = 0; j < 4; ++j) {
        const int r = (wc << 6) + (j << 4) + fr;
        gB[j] = ((((r << 2) | quad) ^ ((r >> 1) & 7)) << 3);
    }

    f32x4_t acc[4][4];
    #pragma unroll
    for (int i = 0; i < 4; ++i)
        #pragma unroll
        for (int j = 0; j < 4; ++j)
            acc[i][j] = (f32x4_t){0.f, 0.f, 0.f, 0.f};

    const int nt = Kd / BKT;

    #define STAGE(t, buf) do {                                                 \
        unsigned short* Al_ = (buf);                                           \
        unsigned short* Bl_ = Al_ + BMT * BKT;                                 \
        const long k0_ = (long)(t) * BKT;                                      \
        load_lds16(Ab + (long)sr * lda + k0_ + sg,         Al_ + (wave << 9)); \
        load_lds16(Ab + (long)(sr + 128) * lda + k0_ + sg,                     \
                   Al_ + 4096 + (wave << 9));                                  \
        load_lds16(Bb + (long)sr * Kd + k0_ + sg,          Bl_ + (wave << 9)); \
    } while (0)

    STAGE(0, lds_buf);
    STAGE(1, lds_buf + LDS_TILE);
    asm volatile("s_waitcnt vmcnt(3)" ::: "memory");
    __builtin_amdgcn_s_barrier();
    __builtin_amdgcn_sched_barrier(0);

    int rb = 0;
    int sbx = 2;
    for (int t = 0; t < nt; ++t) {
        if (t + 2 < nt) STAGE(t + 2, lds_buf + sbx * LDS_TILE);
        const unsigned short* Al = lds_buf + rb * LDS_TILE;
        const unsigned short* Bl = Al + BMT * BKT;
        bf16x8_t af[4], bfr[4];
        #pragma unroll
        for (int i = 0; i < 4; ++i) af[i] = *(const bf16x8_t*)&Al[gA[i]];
        #pragma unroll
        for (int j = 0; j < 4; ++j) bfr[j] = *(const bf16x8_t*)&Bl[gB[j]];
        __builtin_amdgcn_s_setprio(1);
        #pragma unroll
        for (int i = 0; i < 4; ++i)
            #pragma unroll
            for (int j = 0; j < 4; ++j)
                acc[i][j] = __builtin_amdgcn_mfma_f32_16x16x32_bf16(
                    af[i], bfr[j], acc[i][j], 0, 0, 0);
        __builtin_amdgcn_s_setprio(0);
        rb  = (rb == 2)  ? 0 : rb + 1;
        sbx = (sbx == 2) ? 0 : sbx + 1;
        if (t + 1 < nt) {
            if (t + 2 < nt) asm volatile("s_waitcnt vmcnt(3)" ::: "memory");
            else            asm volatile("s_waitcnt vmcnt(0)" ::: "memory");
            __builtin_amdgcn_s_barrier();
            __builtin_amdgcn_sched_barrier(0);
        }
    }
    #undef STAGE

    const int gcol0 = bn * BNT + (wc << 6);
    const int grow0 = bm * BMT + (wr << 6);
    #pragma unroll
    for (int j = 0; j < 4; ++j) {
        const int n = gcol0 + (j << 4) + fr;
        const float bv = bias[n];
        #pragma unroll
        for (int i = 0; i < 4; ++i) {
            #pragma unroll
            for (int r = 0; r < 4; ++r) {
                const int m = grow0 + (i << 4) + (quad << 2) + r;
                float v = acc[i][j][r] + bv;
                if (ACT == 1) v = fmaxf(v, 0.f);
                if (ACT == 2) v = 1.f / (1.f + __expf(-v));
                if (WMODE == 0) {
                    C0u[(long)m * ldc + n] = f2bf(v);
                } else if (WMODE == 1) {
                    const int gm = m0 + m;
                    C1f[((long)(gm >> 6) * 512 + n) * 64 + (gm & 63)] = v;
                    if (n < 256) C0u[(long)m * 256 + n] = f2bf(v);
                } else {
                    const int gm = m0 + m;
                    const int b = gm >> 6, g6 = gm & 63;
                    const int gh = g6 >> 3, gw = g6 & 7;
                    const int c = n >> 8, kh = (n >> 4) & 15, kw = n & 15;
                    const long o = (long)(b * 3 + c) * 16384
                                 + ((gh << 4) + kh) * 128 + (gw << 4) + kw;
                    C0f[o] = v;
                }
            }
        }
    }
}

// ---------- 128x128-tile variant of the SAME R5 pipeline (G2 + G4) ----------
// 256 threads = 4 waves 2x2, per-wave 64x64 (same FLOP/LDS-byte), triple-buffer
// 3x16KiB = 48 KiB -> 3 blocks/CU. Ledger: 4 gloads/tile -> steady vmcnt(4),
// tail vmcnt(0). Swizzle identical. R9 measured: fixed G2's 1-block/CU
// underfill (-24us total). G4: 384 blocks (1.5/CU, imbalanced) -> 768 (3/CU).
template <int ACT, int WMODE>
__global__ void __launch_bounds__(256, 3)
gemm_bt128(const unsigned short* __restrict__ A, int lda,
           const unsigned short* __restrict__ Bt,
           const float* __restrict__ bias,
           unsigned short* __restrict__ C0u,
           float* __restrict__ C0f,
           float* __restrict__ C1f,
           int ldc, int Kd, int nbn, int m0) {
    __shared__ __align__(16) unsigned short lds_buf[3 * 8192];   // 48 KiB
    const int nbm = gridDim.x / nbn;
    const int stripe = nbm >> 3;
    const int xcd = blockIdx.x & 7;
    const int loc = blockIdx.x >> 3;
    const int bm = xcd * stripe + (loc % stripe);
    const int bn = loc / stripe;
    const int tid = threadIdx.x;
    const int wave = tid >> 6;                   // 0..3
    const int lane = tid & 63;
    const int wr = wave >> 1;                    // 0..1 (M)
    const int wc = wave & 1;                     // 0..1 (N)
    const int fr = lane & 15;
    const int quad = lane >> 4;

    const int Gl = tid ^ ((tid >> 3) & 7);       // tid 0..255 -> groups 0..255
    const int sr = Gl >> 2;                      // logical row 0..63
    const int sg = (Gl & 3) << 3;                // logical col elem 0/8/16/24

    const unsigned short* Ab = A + (long)bm * 128 * lda;
    const unsigned short* Bb = Bt + (long)bn * 128 * Kd;

    int gA[4], gB[4];
    #pragma unroll
    for (int i = 0; i < 4; ++i) {
        const int r = (wr << 6) + (i << 4) + fr;
        gA[i] = ((((r << 2) | quad) ^ ((r >> 1) & 7)) << 3);
    }
    #pragma unroll
    for (int j = 0; j < 4; ++j) {
        const int r = (wc << 6) + (j << 4) + fr;
        gB[j] = ((((r << 2) | quad) ^ ((r >> 1) & 7)) << 3);
    }

    f32x4_t acc[4][4];
    #pragma unroll
    for (int i = 0; i < 4; ++i)
        #pragma unroll
        for (int j = 0; j < 4; ++j)
            acc[i][j] = (f32x4_t){0.f, 0.f, 0.f, 0.f};

    const int nt = Kd / 32;

    // 4 gloads/tile: A rows [0,64)+[64,128), B rows [0,64)+[64,128)
    #define STAGE128(t, buf) do {                                              \
        unsigned short* Al_ = (buf);                                           \
        unsigned short* Bl_ = Al_ + 4096;                                      \
        const long k0_ = (long)(t) * 32;                                       \
        load_lds16(Ab + (long)sr * lda + k0_ + sg,        Al_ + (wave << 9));  \
        load_lds16(Ab + (long)(sr + 64) * lda + k0_ + sg,                      \
                   Al_ + 2048 + (wave << 9));                                  \
        load_lds16(Bb + (long)sr * Kd + k0_ + sg,         Bl_ + (wave << 9));  \
        load_lds16(Bb + (long)(sr + 64) * Kd + k0_ + sg,                       \
                   Bl_ + 2048 + (wave << 9));                                  \
    } while (0)

    STAGE128(0, lds_buf);
    STAGE128(1, lds_buf + 8192);
    asm volatile("s_waitcnt vmcnt(4)" ::: "memory");
    __builtin_amdgcn_s_barrier();
    __builtin_amdgcn_sched_barrier(0);

    int rb = 0;
    int sbx = 2;
    for (int t = 0; t < nt; ++t) {
        if (t + 2 < nt) STAGE128(t + 2, lds_buf + sbx * 8192);
        const unsigned short* Al = lds_buf + rb * 8192;
        const unsigned short* Bl = Al + 4096;
        bf16x8_t af[4], bfr[4];
        #pragma unroll
        for (int i = 0; i < 4; ++i) af[i] = *(const bf16x8_t*)&Al[gA[i]];
        #pragma unroll
        for (int j = 0; j < 4; ++j) bfr[j] = *(const bf16x8_t*)&Bl[gB[j]];
        __builtin_amdgcn_s_setprio(1);
        #pragma unroll
        for (int i = 0; i < 4; ++i)
            #pragma unroll
            for (int j = 0; j < 4; ++j)
                acc[i][j] = __builtin_amdgcn_mfma_f32_16x16x32_bf16(
                    af[i], bfr[j], acc[i][j], 0, 0, 0);
        __builtin_amdgcn_s_setprio(0);
        rb  = (rb == 2)  ? 0 : rb + 1;
        sbx = (sbx == 2) ? 0 : sbx + 1;
        if (t + 1 < nt) {
            if (t + 2 < nt) asm volatile("s_waitcnt vmcnt(4)" ::: "memory");
            else            asm volatile("s_waitcnt vmcnt(0)" ::: "memory");
            __builtin_amdgcn_s_barrier();
            __builtin_amdgcn_sched_barrier(0);
        }
    }
    #undef STAGE128

    const int gcol0 = bn * 128 + (wc << 6);
    const int grow0 = bm * 128 + (wr << 6);
    #pragma unroll
    for (int j = 0; j < 4; ++j) {
        const int n = gcol0 + (j << 4) + fr;
        const float bv = bias[n];
        #pragma unroll
        for (int i = 0; i < 4; ++i) {
            #pragma unroll
            for (int r = 0; r < 4; ++r) {
                const int m = grow0 + (i << 4) + (quad << 2) + r;
                float v = acc[i][j][r] + bv;
                if (ACT == 1) v = fmaxf(v, 0.f);
                if (ACT == 2) v = 1.f / (1.f + __expf(-v));
                if (WMODE == 0) {
                    C0u[(long)m * ldc + n] = f2bf(v);
                } else if (WMODE == 1) {
                    const int gm = m0 + m;
                    C1f[((long)(gm >> 6) * 512 + n) * 64 + (gm & 63)] = v;
                    if (n < 256) C0u[(long)m * 256 + n] = f2bf(v);
                } else {
                    const int gm = m0 + m;
                    const int b = gm >> 6, g6 = gm & 63;
                    const int gh = g6 >> 3, gw = g6 & 7;
                    const int c = n >> 8, kh = (n >> 4) & 15, kw = n & 15;
                    const long o = (long)(b * 3 + c) * 16384
                                 + ((gh << 4) + kh) * 128 + (gw << 4) + kw;
                    C0f[o] = v;
                }
            }
        }
    }
}

// ---------- launch ----------
extern "C" void kernel_launch(void* const* d_in, const int* in_sizes, int n_in,
                              void* d_out, int out_size, void* d_ws, size_t ws_size,
                              hipStream_t stream) {
    const float* x      = (const float*)d_in[0];
    const float* w_enc1 = (const float*)d_in[1];
    const float* b_enc1 = (const float*)d_in[2];
    const float* w_enc2 = (const float*)d_in[3];
    const float* b_enc2 = (const float*)d_in[4];
    const float* w_dec1 = (const float*)d_in[5];
    const float* b_dec1 = (const float*)d_in[6];
    const float* w_dec2 = (const float*)d_in[7];
    const float* b_dec2 = (const float*)d_in[8];
    float* outf = (float*)d_out;                      // f32 output
    unsigned short* patches = (unsigned short*)d_out; // patches bf16 in out0 u16 view
    float* out_ml = outf + (long)MM * PP;             // f32 [12.58M, 20.97M)

    const size_t WT_ELEMS = 2048 * 768 + 512 * 2048 + 2048 * 256 + 768 * 2048;
    unsigned short* sb;
    long Mc;
    if (ws_size >= (WT_ELEMS + (size_t)MM * (LL + HID)) * 2) {
        sb = (unsigned short*)d_ws;  Mc = MM;         // 16384 rows, 1 chunk
    } else {
        sb = (unsigned short*)d_in[0]; Mc = 8192;     // x-buffer, 2 chunks
    }
    unsigned short* wT1 = sb;                         // 2048*768
    unsigned short* wT2 = wT1 + 2048 * 768;           // 512*2048
    unsigned short* wT3 = wT2 + 512 * 2048;           // 2048*256
    unsigned short* wT4 = wT3 + 2048 * 256;           // 768*2048
    unsigned short* mu  = wT4 + 768 * 2048;           // Mc*256
    unsigned short* he  = mu + Mc * LL;               // Mc*2048 (hd aliases he)

    patchify<<<6144, 256, 0, stream>>>(x, patches);

    transpose_k<<<(768 / 32) * (2048 / 32), 256, 0, stream>>>(w_enc1, wT1, 768, 2048);
    transpose_k<<<(2048 / 32) * (512 / 32), 256, 0, stream>>>(w_enc2, wT2, 2048, 512);
    transpose_k<<<(256 / 32) * (2048 / 32), 256, 0, stream>>>(w_dec1, wT3, 256, 2048);
    transpose_k<<<(2048 / 32) * (768 / 32), 256, 0, stream>>>(w_dec2, wT4, 2048, 768);

    const int nbm = (int)(Mc / BMT);   // 64 or 32, divisible by 8
    for (long m0 = MM - Mc; m0 >= 0; m0 -= Mc) {
        // he = relu(patches[m0:] @ w_enc1 + b_enc1)      Mc x 2048, K=768
        gemm_bt<1, 0><<<nbm * (HID / BNT), 512, 0, stream>>>(
            patches + m0 * PP, PP, wT1, b_enc1,
            he, nullptr, nullptr, HID, PP, HID / BNT, 0);
        // ml = he @ w_enc2 + b_enc2 -> out1 f32 (transposed) + compact bf16 mu
        // 128x128 variant: (Mc/128)*(512/128) blocks = 512 -> 2 blocks/CU
        gemm_bt128<0, 1><<<(int)(Mc / 128) * (512 / 128), 256, 0, stream>>>(
            he, HID, wT2, b_enc2,
            mu, nullptr, out_ml, 0, HID, 512 / 128, (int)m0);
        // hd = relu(mu @ w_dec1 + b_dec1)                Mc x 2048, K=256
        gemm_bt<1, 0><<<nbm * (HID / BNT), 512, 0, stream>>>(
            mu, LL, wT3, b_dec1,
            he, nullptr, nullptr, HID, LL, HID / BNT, 0);
        // recon rows m0.. = sigmoid(hd @ w_dec2 + b_dec2) -> f32 scatter out0
        // 128x128 variant: (Mc/128)*(768/128) = 768 blocks -> exactly 3/CU
        // (R5 256x128 grid was 384 = 1.5/CU, imbalanced — top dispatch @77us)
        gemm_bt128<2, 2><<<(int)(Mc / 128) * (PP / 128), 256, 0, stream>>>(
            he, HID, wT4, b_dec2,
            nullptr, outf, nullptr, 0, HID, PP / 128, (int)m0);
    }
}

// Round 13
// 351.860 us; speedup vs baseline: 1.0073x; 1.0073x over previous
//
#include <hip/hip_runtime.h>
#include <hip/hip_bf16.h>
#include <stdint.h>

// ---------- types / helpers ----------
typedef __bf16 bf16x8_t __attribute__((ext_vector_type(8)));
typedef float f32x4_t __attribute__((ext_vector_type(4)));
typedef unsigned short ushort8_t __attribute__((ext_vector_type(8)));  // 16B aligned

__device__ __forceinline__ unsigned short f2bf(float f) {
    union { float f; uint32_t i; } v; v.f = f;
    uint32_t i = v.i + (((v.i >> 16) & 1u) + 0x7FFFu);   // RNE
    return (unsigned short)(i >> 16);
}

typedef const __attribute__((address_space(1))) void* gas_t;
typedef __attribute__((address_space(3))) void* las_t;
__device__ __forceinline__ void load_lds16(const unsigned short* g, unsigned short* l) {
    // async global->LDS DMA; LDS dest = wave-uniform base + lane*16B
    __builtin_amdgcn_global_load_lds((gas_t)g, (las_t)l, 16, 0, 0);
}

// ---------- problem constants ----------
#define BB   256
#define CC   3
#define HH   128
#define WW   128
#define PP   768        // C*K*K
#define HID  2048
#define LL   256
#define MM   16384      // B*GH*GW

// ---------- patchify: x f32 (B,C,H,W) -> patches bf16 (M,768), u16-view of out0 ----------
__global__ void patchify(const float* __restrict__ x,
                         unsigned short* __restrict__ patches) {
    int t = blockIdx.x * 256 + threadIdx.x;        // 1,572,864 threads, 8 elems each
    int e = t * 8;                                  // linear index into x
    int col = e & 127;                              // w (multiple of 8)
    int row = (e >> 7) & 127;                       // h
    int c   = (e >> 14) % 3;
    int b   = e / (128 * 128 * 3);
    int gh = row >> 4, kh = row & 15, gw = col >> 4, kw = col & 15;
    long po = (long)(b * 64 + gh * 8 + gw) * PP + c * 256 + kh * 16 + kw;
    float4 v0 = *(const float4*)(x + e);
    float4 v1 = *(const float4*)(x + e + 4);
    ushort8_t o;
    o[0] = f2bf(v0.x); o[1] = f2bf(v0.y); o[2] = f2bf(v0.z); o[3] = f2bf(v0.w);
    o[4] = f2bf(v1.x); o[5] = f2bf(v1.y); o[6] = f2bf(v1.z); o[7] = f2bf(v1.w);
    *(ushort8_t*)(patches + po) = o;
}

// ---------- 32x32-tiled transpose + cast: out bf16[c*R+r] = in f32[r*C+c] ----------
__global__ void transpose_k(const float* __restrict__ in,
                            unsigned short* __restrict__ out, int R, int C) {
    __shared__ unsigned short tile[32][34];
    int nbc = C >> 5;
    int tc = blockIdx.x % nbc, tr = blockIdx.x / nbc;
    int tx = threadIdx.x & 31, ty0 = threadIdx.x >> 5;   // 8 rows/pass
    int r0 = tr << 5, c0 = tc << 5;
    #pragma unroll
    for (int i = 0; i < 4; ++i) {
        int ty = ty0 + i * 8;
        tile[ty][tx] = f2bf(in[(long)(r0 + ty) * C + c0 + tx]);
    }
    __syncthreads();
    #pragma unroll
    for (int i = 0; i < 4; ++i) {
        int ty = ty0 + i * 8;
        out[(long)(c0 + ty) * R + r0 + tx] = tile[tx][ty];
    }
}

// ---------- shared epilogue (C/D layout: col = lane&15, row = (lane>>4)*4+reg) ----------
// WMODE 0: bf16 C0u[m*ldc+n]   1: f32 ml-transpose + compact mu   2: unpatchify
template <int ACT, int WMODE>
__device__ __forceinline__ void epilogue_write(
        float v, int m, int n, int ldc, int m0,
        unsigned short* C0u, float* C0f, float* C1f) {
    if (ACT == 1) v = fmaxf(v, 0.f);
    if (ACT == 2) v = 1.f / (1.f + __expf(-v));
    if (WMODE == 0) {
        C0u[(long)m * ldc + n] = f2bf(v);
    } else if (WMODE == 1) {
        const int gm = m0 + m;
        C1f[((long)(gm >> 6) * 512 + n) * 64 + (gm & 63)] = v;
        if (n < 256) C0u[(long)m * 256 + n] = f2bf(v);
    } else {
        const int gm = m0 + m;
        const int b = gm >> 6, g6 = gm & 63;
        const int gh = g6 >> 3, gw = g6 & 7;
        const int c = n >> 8, kh = (n >> 4) & 15, kw = n & 15;
        const long o = (long)(b * 3 + c) * 16384
                     + ((gh << 4) + kh) * 128 + (gw << 4) + kw;
        C0f[o] = v;
    }
}

// ---------- m97-faithful GEMM (learn_hip m97/m103: 874-912 TF, ref-checked) ----------
// 128x128 tile, BK=64, 256 threads = 4 waves 2x2, per-wave 64x64.
// SINGLE 32 KiB LDS buffer; per K-tile: {8 gload_lds w16; __syncthreads;
// 2 k-halves x (8 ds_read_b128 + 16 MFMA); __syncthreads}. The barrier drain
// is hidden by 4 co-resident blocks (m114 cross-block overlap). BK=64
// halves barrier count vs the R5/R11 BK=32 pipeline (measured plateau 680 TF;
// 3 tilings confirmed — occupancy/vmcnt levers exhausted in that structure).
// LDS swizzle (8 groups/row): logical group L=r*8+g stored at r*8+(g^(r&7));
// DMA dest linear + inverse-swizzled global source (rule #21); read class
// quad^(fr&7) uniform (8 lanes/class) -> wave64-b128 minimum, 0 conflicts.
template <int ACT, int WMODE>
__global__ void __launch_bounds__(256, 4)
gemm_m97(const unsigned short* __restrict__ A, int lda,
         const unsigned short* __restrict__ Bt,
         const float* __restrict__ bias,
         unsigned short* __restrict__ C0u,
         float* __restrict__ C0f,
         float* __restrict__ C1f,
         int ldc, int Kd, int nbn, int m0) {
    __shared__ __align__(16) unsigned short As[128 * 64];   // 16 KiB
    __shared__ __align__(16) unsigned short Bs[128 * 64];   // 16 KiB
    const int nbm = gridDim.x / nbn;
    const int stripe = nbm >> 3;
    const int xcd = blockIdx.x & 7;
    const int loc = blockIdx.x >> 3;
    const int bm = xcd * stripe + (loc % stripe);
    const int bn = loc / stripe;
    const int tid = threadIdx.x;
    const int wave = tid >> 6;                   // 0..3
    const int lane = tid & 63;
    const int wr = wave >> 1;                    // 0..1 (M)
    const int wc = wave & 1;                     // 0..1 (N)
    const int fr = lane & 15;
    const int quad = lane >> 4;

    // staging source swizzle: phys group Gp = i*256 + tid holds logical
    // Gl = Gp ^ ((Gp>>3)&7); bases multiples of 256 -> key bits from tid only
    const int Gl = tid ^ ((tid >> 3) & 7);
    const int srow = Gl >> 3;                    // 0..31 (+32 per inst)
    const int scol = (Gl & 7) << 3;              // k-elem 0..56

    const unsigned short* Ab = A + (long)bm * 128 * lda;
    const unsigned short* Bb = Bt + (long)bn * 128 * Kd;

    // fragment read offsets (elems): row r, kgroup g -> r*64 + ((g^(r&7))<<3)
    int aoff[4], boff[4];
    #pragma unroll
    for (int i = 0; i < 4; ++i) {
        aoff[i] = ((wr << 6) + (i << 4) + fr) << 6;
        boff[i] = ((wc << 6) + (i << 4) + fr) << 6;
    }
    const int gx0 = ((quad)     ^ (fr & 7)) << 3;   // k-half 0 (kgroups 0..3)
    const int gx1 = ((quad | 4) ^ (fr & 7)) << 3;   // k-half 1 (kgroups 4..7)

    f32x4_t acc[4][4];
    #pragma unroll
    for (int i = 0; i < 4; ++i)
        #pragma unroll
        for (int j = 0; j < 4; ++j)
            acc[i][j] = (f32x4_t){0.f, 0.f, 0.f, 0.f};

    const int nt = Kd / 64;                      // 12 (G1) / 32 (G4)

    for (int t = 0; t < nt; ++t) {
        const long k0 = (long)t * 64;
        #pragma unroll
        for (int i = 0; i < 4; ++i) {            // 8 gload_lds w16 / wave
            load_lds16(Ab + (long)(srow + (i << 5)) * lda + k0 + scol,
                       As + (i << 11) + (wave << 9));
            load_lds16(Bb + (long)(srow + (i << 5)) * Kd + k0 + scol,
                       Bs + (i << 11) + (wave << 9));
        }
        __syncthreads();                         // drains vmcnt -> tile ready
        #pragma unroll
        for (int h = 0; h < 2; ++h) {
            const int gx = h ? gx1 : gx0;
            bf16x8_t af[4], bfr[4];
            #pragma unroll
            for (int i = 0; i < 4; ++i) af[i] = *(const bf16x8_t*)&As[aoff[i] + gx];
            #pragma unroll
            for (int j = 0; j < 4; ++j) bfr[j] = *(const bf16x8_t*)&Bs[boff[j] + gx];
            #pragma unroll
            for (int i = 0; i < 4; ++i)
                #pragma unroll
                for (int j = 0; j < 4; ++j)
                    acc[i][j] = __builtin_amdgcn_mfma_f32_16x16x32_bf16(
                        af[i], bfr[j], acc[i][j], 0, 0, 0);
        }
        __syncthreads();                         // all reads done before restage
    }

    const int gcol0 = bn * 128 + (wc << 6);
    const int grow0 = bm * 128 + (wr << 6);
    #pragma unroll
    for (int j = 0; j < 4; ++j) {
        const int n = gcol0 + (j << 4) + fr;
        const float bv = bias[n];
        #pragma unroll
        for (int i = 0; i < 4; ++i)
            #pragma unroll
            for (int r = 0; r < 4; ++r) {
                const int m = grow0 + (i << 4) + (quad << 2) + r;
                epilogue_write<ACT, WMODE>(acc[i][j][r] + bv, m, n, ldc, m0,
                                           C0u, C0f, C1f);
            }
    }
}

// ---------- R5-pipeline 128x128 variant (G2 — measured good since R9) ----------
// 256 threads = 4 waves 2x2, triple-buffer 3x16KiB, counted vmcnt(4).
template <int ACT, int WMODE>
__global__ void __launch_bounds__(256, 3)
gemm_bt128(const unsigned short* __restrict__ A, int lda,
           const unsigned short* __restrict__ Bt,
           const float* __restrict__ bias,
           unsigned short* __restrict__ C0u,
           float* __restrict__ C0f,
           float* __restrict__ C1f,
           int ldc, int Kd, int nbn, int m0) {
    __shared__ __align__(16) unsigned short lds_buf[3 * 8192];   // 48 KiB
    const int nbm = gridDim.x / nbn;
    const int stripe = nbm >> 3;
    const int xcd = blockIdx.x & 7;
    const int loc = blockIdx.x >> 3;
    const int bm = xcd * stripe + (loc % stripe);
    const int bn = loc / stripe;
    const int tid = threadIdx.x;
    const int wave = tid >> 6;
    const int lane = tid & 63;
    const int wr = wave >> 1;
    const int wc = wave & 1;
    const int fr = lane & 15;
    const int quad = lane >> 4;

    const int Gl = tid ^ ((tid >> 3) & 7);
    const int sr = Gl >> 2;                      // logical row 0..63
    const int sg = (Gl & 3) << 3;                // col elem 0/8/16/24

    const unsigned short* Ab = A + (long)bm * 128 * lda;
    const unsigned short* Bb = Bt + (long)bn * 128 * Kd;

    int gA[4], gB[4];
    #pragma unroll
    for (int i = 0; i < 4; ++i) {
        const int r = (wr << 6) + (i << 4) + fr;
        gA[i] = ((((r << 2) | quad) ^ ((r >> 1) & 7)) << 3);
    }
    #pragma unroll
    for (int j = 0; j < 4; ++j) {
        const int r = (wc << 6) + (j << 4) + fr;
        gB[j] = ((((r << 2) | quad) ^ ((r >> 1) & 7)) << 3);
    }

    f32x4_t acc[4][4];
    #pragma unroll
    for (int i = 0; i < 4; ++i)
        #pragma unroll
        for (int j = 0; j < 4; ++j)
            acc[i][j] = (f32x4_t){0.f, 0.f, 0.f, 0.f};

    const int nt = Kd / 32;

    #define STAGE128(t, buf) do {                                              \
        unsigned short* Al_ = (buf);                                           \
        unsigned short* Bl_ = Al_ + 4096;                                      \
        const long k0_ = (long)(t) * 32;                                       \
        load_lds16(Ab + (long)sr * lda + k0_ + sg,        Al_ + (wave << 9));  \
        load_lds16(Ab + (long)(sr + 64) * lda + k0_ + sg,                      \
                   Al_ + 2048 + (wave << 9));                                  \
        load_lds16(Bb + (long)sr * Kd + k0_ + sg,         Bl_ + (wave << 9));  \
        load_lds16(Bb + (long)(sr + 64) * Kd + k0_ + sg,                       \
                   Bl_ + 2048 + (wave << 9));                                  \
    } while (0)

    STAGE128(0, lds_buf);
    STAGE128(1, lds_buf + 8192);
    asm volatile("s_waitcnt vmcnt(4)" ::: "memory");
    __builtin_amdgcn_s_barrier();
    __builtin_amdgcn_sched_barrier(0);

    int rb = 0;
    int sbx = 2;
    for (int t = 0; t < nt; ++t) {
        if (t + 2 < nt) STAGE128(t + 2, lds_buf + sbx * 8192);
        const unsigned short* Al = lds_buf + rb * 8192;
        const unsigned short* Bl = Al + 4096;
        bf16x8_t af[4], bfr[4];
        #pragma unroll
        for (int i = 0; i < 4; ++i) af[i] = *(const bf16x8_t*)&Al[gA[i]];
        #pragma unroll
        for (int j = 0; j < 4; ++j) bfr[j] = *(const bf16x8_t*)&Bl[gB[j]];
        __builtin_amdgcn_s_setprio(1);
        #pragma unroll
        for (int i = 0; i < 4; ++i)
            #pragma unroll
            for (int j = 0; j < 4; ++j)
                acc[i][j] = __builtin_amdgcn_mfma_f32_16x16x32_bf16(
                    af[i], bfr[j], acc[i][j], 0, 0, 0);
        __builtin_amdgcn_s_setprio(0);
        rb  = (rb == 2)  ? 0 : rb + 1;
        sbx = (sbx == 2) ? 0 : sbx + 1;
        if (t + 1 < nt) {
            if (t + 2 < nt) asm volatile("s_waitcnt vmcnt(4)" ::: "memory");
            else            asm volatile("s_waitcnt vmcnt(0)" ::: "memory");
            __builtin_amdgcn_s_barrier();
            __builtin_amdgcn_sched_barrier(0);
        }
    }
    #undef STAGE128

    const int gcol0 = bn * 128 + (wc << 6);
    const int grow0 = bm * 128 + (wr << 6);
    #pragma unroll
    for (int j = 0; j < 4; ++j) {
        const int n = gcol0 + (j << 4) + fr;
        const float bv = bias[n];
        #pragma unroll
        for (int i = 0; i < 4; ++i)
            #pragma unroll
            for (int r = 0; r < 4; ++r) {
                const int m = grow0 + (i << 4) + (quad << 2) + r;
                epilogue_write<ACT, WMODE>(acc[i][j][r] + bv, m, n, ldc, m0,
                                           C0u, C0f, C1f);
            }
    }
}

// ---------- R5-pipeline 256x128 (G3) ----------
#define BMT 256
#define BNT 128
#define BKT 32
#define LDS_TILE ((BMT + BNT) * BKT)   // 24 KiB per buffer

template <int ACT, int WMODE>
__global__ void __launch_bounds__(512, 4)
gemm_bt(const unsigned short* __restrict__ A, int lda,
        const unsigned short* __restrict__ Bt,
        const float* __restrict__ bias,
        unsigned short* __restrict__ C0u,
        float* __restrict__ C0f,
        float* __restrict__ C1f,
        int ldc, int Kd, int nbn, int m0) {
    __shared__ __align__(16) unsigned short lds_buf[3 * LDS_TILE];   // 72 KiB
    const int nbm = gridDim.x / nbn;
    const int stripe = nbm >> 3;
    const int xcd = blockIdx.x & 7;
    const int loc = blockIdx.x >> 3;
    const int bm = xcd * stripe + (loc % stripe);
    const int bn = loc / stripe;
    const int tid = threadIdx.x;
    const int wave = tid >> 6;
    const int lane = tid & 63;
    const int wr = wave >> 1;                    // 0..3 (M)
    const int wc = wave & 1;                     // 0..1 (N)
    const int fr = lane & 15;
    const int quad = lane >> 4;

    const int Gl = tid ^ ((tid >> 3) & 7);
    const int sr = Gl >> 2;                      // logical row 0..127
    const int sg = (Gl & 3) << 3;

    const unsigned short* Ab = A + (long)bm * BMT * lda;
    const unsigned short* Bb = Bt + (long)bn * BNT * Kd;

    int gA[4], gB[4];
    #pragma unroll
    for (int i = 0; i < 4; ++i) {
        const int r = (wr << 6) + (i << 4) + fr;
        gA[i] = ((((r << 2) | quad) ^ ((r >> 1) & 7)) << 3);
    }
    #pragma unroll
    for (int j = 0; j < 4; ++j) {
        const int r = (wc << 6) + (j << 4) + fr;
        gB[j] = ((((r << 2) | quad) ^ ((r >> 1) & 7)) << 3);
    }

    f32x4_t acc[4][4];
    #pragma unroll
    for (int i = 0; i < 4; ++i)
        #pragma unroll
        for (int j = 0; j < 4; ++j)
            acc[i][j] = (f32x4_t){0.f, 0.f, 0.f, 0.f};

    const int nt = Kd / BKT;

    #define STAGE(t, buf) do {                                                 \
        unsigned short* Al_ = (buf);                                           \
        unsigned short* Bl_ = Al_ + BMT * BKT;                                 \
        const long k0_ = (long)(t) * BKT;                                      \
        load_lds16(Ab + (long)sr * lda + k0_ + sg,         Al_ + (wave << 9)); \
        load_lds16(Ab + (long)(sr + 128) * lda + k0_ + sg,                     \
                   Al_ + 4096 + (wave << 9));                                  \
        load_lds16(Bb + (long)sr * Kd + k0_ + sg,          Bl_ + (wave << 9)); \
    } while (0)

    STAGE(0, lds_buf);
    STAGE(1, lds_buf + LDS_TILE);
    asm volatile("s_waitcnt vmcnt(3)" ::: "memory");
    __builtin_amdgcn_s_barrier();
    __builtin_amdgcn_sched_barrier(0);

    int rb = 0;
    int sbx = 2;
    for (int t = 0; t < nt; ++t) {
        if (t + 2 < nt) STAGE(t + 2, lds_buf + sbx * LDS_TILE);
        const unsigned short* Al = lds_buf + rb * LDS_TILE;
        const unsigned short* Bl = Al + BMT * BKT;
        bf16x8_t af[4], bfr[4];
        #pragma unroll
        for (int i = 0; i < 4; ++i) af[i] = *(const bf16x8_t*)&Al[gA[i]];
        #pragma unroll
        for (int j = 0; j < 4; ++j) bfr[j] = *(const bf16x8_t*)&Bl[gB[j]];
        __builtin_amdgcn_s_setprio(1);
        #pragma unroll
        for (int i = 0; i < 4; ++i)
            #pragma unroll
            for (int j = 0; j < 4; ++j)
                acc[i][j] = __builtin_amdgcn_mfma_f32_16x16x32_bf16(
                    af[i], bfr[j], acc[i][j], 0, 0, 0);
        __builtin_amdgcn_s_setprio(0);
        rb  = (rb == 2)  ? 0 : rb + 1;
        sbx = (sbx == 2) ? 0 : sbx + 1;
        if (t + 1 < nt) {
            if (t + 2 < nt) asm volatile("s_waitcnt vmcnt(3)" ::: "memory");
            else            asm volatile("s_waitcnt vmcnt(0)" ::: "memory");
            __builtin_amdgcn_s_barrier();
            __builtin_amdgcn_sched_barrier(0);
        }
    }
    #undef STAGE

    const int gcol0 = bn * BNT + (wc << 6);
    const int grow0 = bm * BMT + (wr << 6);
    #pragma unroll
    for (int j = 0; j < 4; ++j) {
        const int n = gcol0 + (j << 4) + fr;
        const float bv = bias[n];
        #pragma unroll
        for (int i = 0; i < 4; ++i)
            #pragma unroll
            for (int r = 0; r < 4; ++r) {
                const int m = grow0 + (i << 4) + (quad << 2) + r;
                epilogue_write<ACT, WMODE>(acc[i][j][r] + bv, m, n, ldc, m0,
                                           C0u, C0f, C1f);
            }
    }
}

// ---------- launch ----------
extern "C" void kernel_launch(void* const* d_in, const int* in_sizes, int n_in,
                              void* d_out, int out_size, void* d_ws, size_t ws_size,
                              hipStream_t stream) {
    const float* x      = (const float*)d_in[0];
    const float* w_enc1 = (const float*)d_in[1];
    const float* b_enc1 = (const float*)d_in[2];
    const float* w_enc2 = (const float*)d_in[3];
    const float* b_enc2 = (const float*)d_in[4];
    const float* w_dec1 = (const float*)d_in[5];
    const float* b_dec1 = (const float*)d_in[6];
    const float* w_dec2 = (const float*)d_in[7];
    const float* b_dec2 = (const float*)d_in[8];
    float* outf = (float*)d_out;                      // f32 output
    unsigned short* patches = (unsigned short*)d_out; // patches bf16 in out0 u16 view
    float* out_ml = outf + (long)MM * PP;             // f32 [12.58M, 20.97M)

    const size_t WT_ELEMS = 2048 * 768 + 512 * 2048 + 2048 * 256 + 768 * 2048;
    unsigned short* sb;
    long Mc;
    if (ws_size >= (WT_ELEMS + (size_t)MM * (LL + HID)) * 2) {
        sb = (unsigned short*)d_ws;  Mc = MM;         // 16384 rows, 1 chunk
    } else {
        sb = (unsigned short*)d_in[0]; Mc = 8192;     // x-buffer, 2 chunks
    }
    unsigned short* wT1 = sb;                         // 2048*768
    unsigned short* wT2 = wT1 + 2048 * 768;           // 512*2048
    unsigned short* wT3 = wT2 + 512 * 2048;           // 2048*256
    unsigned short* wT4 = wT3 + 2048 * 256;           // 768*2048
    unsigned short* mu  = wT4 + 768 * 2048;           // Mc*256
    unsigned short* he  = mu + Mc * LL;               // Mc*2048 (hd aliases he)

    patchify<<<6144, 256, 0, stream>>>(x, patches);

    transpose_k<<<(768 / 32) * (2048 / 32), 256, 0, stream>>>(w_enc1, wT1, 768, 2048);
    transpose_k<<<(2048 / 32) * (512 / 32), 256, 0, stream>>>(w_enc2, wT2, 2048, 512);
    transpose_k<<<(256 / 32) * (2048 / 32), 256, 0, stream>>>(w_dec1, wT3, 256, 2048);
    transpose_k<<<(2048 / 32) * (768 / 32), 256, 0, stream>>>(w_dec2, wT4, 2048, 768);

    for (long m0 = MM - Mc; m0 >= 0; m0 -= Mc) {
        // he = relu(patches[m0:] @ w_enc1 + b_enc1)      Mc x 2048, K=768
        // m97-style: (Mc/128)*(2048/128) = 2048 blocks, 4 blocks/CU
        gemm_m97<1, 0><<<(int)(Mc / 128) * (HID / 128), 256, 0, stream>>>(
            patches + m0 * PP, PP, wT1, b_enc1,
            he, nullptr, nullptr, HID, PP, HID / 128, 0);
        // ml = he @ w_enc2 + b_enc2 -> out1 f32 (transposed) + compact bf16 mu
        gemm_bt128<0, 1><<<(int)(Mc / 128) * (512 / 128), 256, 0, stream>>>(
            he, HID, wT2, b_enc2,
            mu, nullptr, out_ml, 0, HID, 512 / 128, (int)m0);
        // hd = relu(mu @ w_dec1 + b_dec1)                Mc x 2048, K=256
        gemm_bt<1, 0><<<(int)(Mc / BMT) * (HID / BNT), 512, 0, stream>>>(
            mu, LL, wT3, b_dec1,
            he, nullptr, nullptr, HID, LL, HID / BNT, 0);
        // recon rows m0.. = sigmoid(hd @ w_dec2 + b_dec2) -> f32 scatter out0
        // m97-style: (Mc/128)*(768/128) = 768 blocks
        gemm_m97<2, 2><<<(int)(Mc / 128) * (PP / 128), 256, 0, stream>>>(
            he, HID, wT4, b_dec2,
            nullptr, outf, nullptr, 0, HID, PP / 128, (int)m0);
    }
}

// Round 14
// 350.774 us; speedup vs baseline: 1.0104x; 1.0031x over previous
//
#include <hip/hip_runtime.h>
#include <hip/hip_bf16.h>
#include <stdint.h>

// ---------- types / helpers ----------
typedef __bf16 bf16x8_t __attribute__((ext_vector_type(8)));
typedef float f32x4_t __attribute__((ext_vector_type(4)));
typedef unsigned short ushort8_t __attribute__((ext_vector_type(8)));  // 16B aligned

__device__ __forceinline__ unsigned short f2bf(float f) {
    union { float f; uint32_t i; } v; v.f = f;
    uint32_t i = v.i + (((v.i >> 16) & 1u) + 0x7FFFu);   // RNE
    return (unsigned short)(i >> 16);
}

typedef const __attribute__((address_space(1))) void* gas_t;
typedef __attribute__((address_space(3))) void* las_t;
__device__ __forceinline__ void load_lds16(const unsigned short* g, unsigned short* l) {
    // async global->LDS DMA; LDS dest = wave-uniform base + lane*16B
    __builtin_amdgcn_global_load_lds((gas_t)g, (las_t)l, 16, 0, 0);
}

// ---------- problem constants ----------
#define BB   256
#define CC   3
#define HH   128
#define WW   128
#define PP   768        // C*K*K
#define HID  2048
#define LL   256
#define MM   16384      // B*GH*GW

// ---------- patchify: x f32 (B,C,H,W) -> patches bf16 (M,768), u16-view of out0 ----------
__global__ void patchify(const float* __restrict__ x,
                         unsigned short* __restrict__ patches) {
    int t = blockIdx.x * 256 + threadIdx.x;        // 1,572,864 threads, 8 elems each
    int e = t * 8;                                  // linear index into x
    int col = e & 127;                              // w (multiple of 8)
    int row = (e >> 7) & 127;                       // h
    int c   = (e >> 14) % 3;
    int b   = e / (128 * 128 * 3);
    int gh = row >> 4, kh = row & 15, gw = col >> 4, kw = col & 15;
    long po = (long)(b * 64 + gh * 8 + gw) * PP + c * 256 + kh * 16 + kw;
    float4 v0 = *(const float4*)(x + e);
    float4 v1 = *(const float4*)(x + e + 4);
    ushort8_t o;
    o[0] = f2bf(v0.x); o[1] = f2bf(v0.y); o[2] = f2bf(v0.z); o[3] = f2bf(v0.w);
    o[4] = f2bf(v1.x); o[5] = f2bf(v1.y); o[6] = f2bf(v1.z); o[7] = f2bf(v1.w);
    *(ushort8_t*)(patches + po) = o;
}

// ---------- 32x32-tiled transpose + cast: out bf16[c*R+r] = in f32[r*C+c] ----------
__global__ void transpose_k(const float* __restrict__ in,
                            unsigned short* __restrict__ out, int R, int C) {
    __shared__ unsigned short tile[32][34];
    int nbc = C >> 5;
    int tc = blockIdx.x % nbc, tr = blockIdx.x / nbc;
    int tx = threadIdx.x & 31, ty0 = threadIdx.x >> 5;   // 8 rows/pass
    int r0 = tr << 5, c0 = tc << 5;
    #pragma unroll
    for (int i = 0; i < 4; ++i) {
        int ty = ty0 + i * 8;
        tile[ty][tx] = f2bf(in[(long)(r0 + ty) * C + c0 + tx]);
    }
    __syncthreads();
    #pragma unroll
    for (int i = 0; i < 4; ++i) {
        int ty = ty0 + i * 8;
        out[(long)(c0 + ty) * R + r0 + tx] = tile[tx][ty];
    }
}

// ---------- shared epilogue (C/D layout: col = lane&15, row = (lane>>4)*4+reg) ----------
// WMODE 0: bf16 C0u[m*ldc+n]   1: f32 ml-transpose + compact mu   2: unpatchify
template <int ACT, int WMODE>
__device__ __forceinline__ void epilogue_write(
        float v, int m, int n, int ldc, int m0,
        unsigned short* C0u, float* C0f, float* C1f) {
    if (ACT == 1) v = fmaxf(v, 0.f);
    if (ACT == 2) v = 1.f / (1.f + __expf(-v));
    if (WMODE == 0) {
        C0u[(long)m * ldc + n] = f2bf(v);
    } else if (WMODE == 1) {
        const int gm = m0 + m;
        C1f[((long)(gm >> 6) * 512 + n) * 64 + (gm & 63)] = v;
        if (n < 256) C0u[(long)m * 256 + n] = f2bf(v);
    } else {
        const int gm = m0 + m;
        const int b = gm >> 6, g6 = gm & 63;
        const int gh = g6 >> 3, gw = g6 & 7;
        const int c = n >> 8, kh = (n >> 4) & 15, kw = n & 15;
        const long o = (long)(b * 3 + c) * 16384
                     + ((gh << 4) + kh) * 128 + (gw << 4) + kw;
        C0f[o] = v;
    }
}

// ---------- m97-faithful GEMM (learn_hip m97/m103: 874-912 TF, ref-checked) ----------
// 128x128 tile, BK=64, 256 threads = 4 waves 2x2, per-wave 64x64.
// SINGLE 32 KiB LDS buffer; per K-tile: {8 gload_lds w16; __syncthreads;
// 2 k-halves x (8 ds_read_b128 + 16 MFMA); __syncthreads}. Barrier drain
// hidden by 4 co-resident blocks (m114 cross-block overlap).
// Measured here (R13): G1 66.4us = 775 TF, MfmaUtil 30.6%, 0 conflicts —
// best per-dispatch GEMM of the session; now used for G1, G3, G4.
// LDS swizzle (8 groups/row): logical group L=r*8+g stored at r*8+(g^(r&7));
// DMA dest linear + inverse-swizzled global source (rule #21); read class
// quad^(fr&7) uniform (8 lanes/class) -> wave64-b128 minimum, 0 conflicts.
template <int ACT, int WMODE>
__global__ void __launch_bounds__(256, 4)
gemm_m97(const unsigned short* __restrict__ A, int lda,
         const unsigned short* __restrict__ Bt,
         const float* __restrict__ bias,
         unsigned short* __restrict__ C0u,
         float* __restrict__ C0f,
         float* __restrict__ C1f,
         int ldc, int Kd, int nbn, int m0) {
    __shared__ __align__(16) unsigned short As[128 * 64];   // 16 KiB
    __shared__ __align__(16) unsigned short Bs[128 * 64];   // 16 KiB
    const int nbm = gridDim.x / nbn;
    const int stripe = nbm >> 3;
    const int xcd = blockIdx.x & 7;
    const int loc = blockIdx.x >> 3;
    const int bm = xcd * stripe + (loc % stripe);
    const int bn = loc / stripe;
    const int tid = threadIdx.x;
    const int wave = tid >> 6;                   // 0..3
    const int lane = tid & 63;
    const int wr = wave >> 1;                    // 0..1 (M)
    const int wc = wave & 1;                     // 0..1 (N)
    const int fr = lane & 15;
    const int quad = lane >> 4;

    // staging source swizzle: phys group Gp = i*256 + tid holds logical
    // Gl = Gp ^ ((Gp>>3)&7); bases multiples of 256 -> key bits from tid only
    const int Gl = tid ^ ((tid >> 3) & 7);
    const int srow = Gl >> 3;                    // 0..31 (+32 per inst)
    const int scol = (Gl & 7) << 3;              // k-elem 0..56

    const unsigned short* Ab = A + (long)bm * 128 * lda;
    const unsigned short* Bb = Bt + (long)bn * 128 * Kd;

    // fragment read offsets (elems): row r, kgroup g -> r*64 + ((g^(r&7))<<3)
    int aoff[4], boff[4];
    #pragma unroll
    for (int i = 0; i < 4; ++i) {
        aoff[i] = ((wr << 6) + (i << 4) + fr) << 6;
        boff[i] = ((wc << 6) + (i << 4) + fr) << 6;
    }
    const int gx0 = ((quad)     ^ (fr & 7)) << 3;   // k-half 0 (kgroups 0..3)
    const int gx1 = ((quad | 4) ^ (fr & 7)) << 3;   // k-half 1 (kgroups 4..7)

    f32x4_t acc[4][4];
    #pragma unroll
    for (int i = 0; i < 4; ++i)
        #pragma unroll
        for (int j = 0; j < 4; ++j)
            acc[i][j] = (f32x4_t){0.f, 0.f, 0.f, 0.f};

    const int nt = Kd / 64;                      // 12 (G1) / 4 (G3) / 32 (G4)

    for (int t = 0; t < nt; ++t) {
        const long k0 = (long)t * 64;
        #pragma unroll
        for (int i = 0; i < 4; ++i) {            // 8 gload_lds w16 / wave
            load_lds16(Ab + (long)(srow + (i << 5)) * lda + k0 + scol,
                       As + (i << 11) + (wave << 9));
            load_lds16(Bb + (long)(srow + (i << 5)) * Kd + k0 + scol,
                       Bs + (i << 11) + (wave << 9));
        }
        __syncthreads();                         // drains vmcnt -> tile ready
        #pragma unroll
        for (int h = 0; h < 2; ++h) {
            const int gx = h ? gx1 : gx0;
            bf16x8_t af[4], bfr[4];
            #pragma unroll
            for (int i = 0; i < 4; ++i) af[i] = *(const bf16x8_t*)&As[aoff[i] + gx];
            #pragma unroll
            for (int j = 0; j < 4; ++j) bfr[j] = *(const bf16x8_t*)&Bs[boff[j] + gx];
            #pragma unroll
            for (int i = 0; i < 4; ++i)
                #pragma unroll
                for (int j = 0; j < 4; ++j)
                    acc[i][j] = __builtin_amdgcn_mfma_f32_16x16x32_bf16(
                        af[i], bfr[j], acc[i][j], 0, 0, 0);
        }
        __syncthreads();                         // all reads done before restage
    }

    const int gcol0 = bn * 128 + (wc << 6);
    const int grow0 = bm * 128 + (wr << 6);
    #pragma unroll
    for (int j = 0; j < 4; ++j) {
        const int n = gcol0 + (j << 4) + fr;
        const float bv = bias[n];
        #pragma unroll
        for (int i = 0; i < 4; ++i)
            #pragma unroll
            for (int r = 0; r < 4; ++r) {
                const int m = grow0 + (i << 4) + (quad << 2) + r;
                epilogue_write<ACT, WMODE>(acc[i][j][r] + bv, m, n, ldc, m0,
                                           C0u, C0f, C1f);
            }
    }
}

// ---------- R5-pipeline 128x128 variant (G2 — measured good since R9) ----------
// 256 threads = 4 waves 2x2, triple-buffer 3x16KiB, counted vmcnt(4).
// Kept for G2: its grid is only 512 blocks (N=512), where this 2-block/CU
// pipelined form is the measured best; m97's 4/CU overlap can't apply.
template <int ACT, int WMODE>
__global__ void __launch_bounds__(256, 3)
gemm_bt128(const unsigned short* __restrict__ A, int lda,
           const unsigned short* __restrict__ Bt,
           const float* __restrict__ bias,
           unsigned short* __restrict__ C0u,
           float* __restrict__ C0f,
           float* __restrict__ C1f,
           int ldc, int Kd, int nbn, int m0) {
    __shared__ __align__(16) unsigned short lds_buf[3 * 8192];   // 48 KiB
    const int nbm = gridDim.x / nbn;
    const int stripe = nbm >> 3;
    const int xcd = blockIdx.x & 7;
    const int loc = blockIdx.x >> 3;
    const int bm = xcd * stripe + (loc % stripe);
    const int bn = loc / stripe;
    const int tid = threadIdx.x;
    const int wave = tid >> 6;
    const int lane = tid & 63;
    const int wr = wave >> 1;
    const int wc = wave & 1;
    const int fr = lane & 15;
    const int quad = lane >> 4;

    const int Gl = tid ^ ((tid >> 3) & 7);
    const int sr = Gl >> 2;                      // logical row 0..63
    const int sg = (Gl & 3) << 3;                // col elem 0/8/16/24

    const unsigned short* Ab = A + (long)bm * 128 * lda;
    const unsigned short* Bb = Bt + (long)bn * 128 * Kd;

    int gA[4], gB[4];
    #pragma unroll
    for (int i = 0; i < 4; ++i) {
        const int r = (wr << 6) + (i << 4) + fr;
        gA[i] = ((((r << 2) | quad) ^ ((r >> 1) & 7)) << 3);
    }
    #pragma unroll
    for (int j = 0; j < 4; ++j) {
        const int r = (wc << 6) + (j << 4) + fr;
        gB[j] = ((((r << 2) | quad) ^ ((r >> 1) & 7)) << 3);
    }

    f32x4_t acc[4][4];
    #pragma unroll
    for (int i = 0; i < 4; ++i)
        #pragma unroll
        for (int j = 0; j < 4; ++j)
            acc[i][j] = (f32x4_t){0.f, 0.f, 0.f, 0.f};

    const int nt = Kd / 32;

    #define STAGE128(t, buf) do {                                              \
        unsigned short* Al_ = (buf);                                           \
        unsigned short* Bl_ = Al_ + 4096;                                      \
        const long k0_ = (long)(t) * 32;                                       \
        load_lds16(Ab + (long)sr * lda + k0_ + sg,        Al_ + (wave << 9));  \
        load_lds16(Ab + (long)(sr + 64) * lda + k0_ + sg,                      \
                   Al_ + 2048 + (wave << 9));                                  \
        load_lds16(Bb + (long)sr * Kd + k0_ + sg,         Bl_ + (wave << 9));  \
        load_lds16(Bb + (long)(sr + 64) * Kd + k0_ + sg,                       \
                   Bl_ + 2048 + (wave << 9));                                  \
    } while (0)

    STAGE128(0, lds_buf);
    STAGE128(1, lds_buf + 8192);
    asm volatile("s_waitcnt vmcnt(4)" ::: "memory");
    __builtin_amdgcn_s_barrier();
    __builtin_amdgcn_sched_barrier(0);

    int rb = 0;
    int sbx = 2;
    for (int t = 0; t < nt; ++t) {
        if (t + 2 < nt) STAGE128(t + 2, lds_buf + sbx * 8192);
        const unsigned short* Al = lds_buf + rb * 8192;
        const unsigned short* Bl = Al + 4096;
        bf16x8_t af[4], bfr[4];
        #pragma unroll
        for (int i = 0; i < 4; ++i) af[i] = *(const bf16x8_t*)&Al[gA[i]];
        #pragma unroll
        for (int j = 0; j < 4; ++j) bfr[j] = *(const bf16x8_t*)&Bl[gB[j]];
        __builtin_amdgcn_s_setprio(1);
        #pragma unroll
        for (int i = 0; i < 4; ++i)
            #pragma unroll
            for (int j = 0; j < 4; ++j)
                acc[i][j] = __builtin_amdgcn_mfma_f32_16x16x32_bf16(
                    af[i], bfr[j], acc[i][j], 0, 0, 0);
        __builtin_amdgcn_s_setprio(0);
        rb  = (rb == 2)  ? 0 : rb + 1;
        sbx = (sbx == 2) ? 0 : sbx + 1;
        if (t + 1 < nt) {
            if (t + 2 < nt) asm volatile("s_waitcnt vmcnt(4)" ::: "memory");
            else            asm volatile("s_waitcnt vmcnt(0)" ::: "memory");
            __builtin_amdgcn_s_barrier();
            __builtin_amdgcn_sched_barrier(0);
        }
    }
    #undef STAGE128

    const int gcol0 = bn * 128 + (wc << 6);
    const int grow0 = bm * 128 + (wr << 6);
    #pragma unroll
    for (int j = 0; j < 4; ++j) {
        const int n = gcol0 + (j << 4) + fr;
        const float bv = bias[n];
        #pragma unroll
        for (int i = 0; i < 4; ++i)
            #pragma unroll
            for (int r = 0; r < 4; ++r) {
                const int m = grow0 + (i << 4) + (quad << 2) + r;
                epilogue_write<ACT, WMODE>(acc[i][j][r] + bv, m, n, ldc, m0,
                                           C0u, C0f, C1f);
            }
    }
}

// ---------- launch ----------
extern "C" void kernel_launch(void* const* d_in, const int* in_sizes, int n_in,
                              void* d_out, int out_size, void* d_ws, size_t ws_size,
                              hipStream_t stream) {
    const float* x      = (const float*)d_in[0];
    const float* w_enc1 = (const float*)d_in[1];
    const float* b_enc1 = (const float*)d_in[2];
    const float* w_enc2 = (const float*)d_in[3];
    const float* b_enc2 = (const float*)d_in[4];
    const float* w_dec1 = (const float*)d_in[5];
    const float* b_dec1 = (const float*)d_in[6];
    const float* w_dec2 = (const float*)d_in[7];
    const float* b_dec2 = (const float*)d_in[8];
    float* outf = (float*)d_out;                      // f32 output
    unsigned short* patches = (unsigned short*)d_out; // patches bf16 in out0 u16 view
    float* out_ml = outf + (long)MM * PP;             // f32 [12.58M, 20.97M)

    const size_t WT_ELEMS = 2048 * 768 + 512 * 2048 + 2048 * 256 + 768 * 2048;
    unsigned short* sb;
    long Mc;
    if (ws_size >= (WT_ELEMS + (size_t)MM * (LL + HID)) * 2) {
        sb = (unsigned short*)d_ws;  Mc = MM;         // 16384 rows, 1 chunk
    } else {
        sb = (unsigned short*)d_in[0]; Mc = 8192;     // x-buffer, 2 chunks
    }
    unsigned short* wT1 = sb;                         // 2048*768
    unsigned short* wT2 = wT1 + 2048 * 768;           // 512*2048
    unsigned short* wT3 = wT2 + 512 * 2048;           // 2048*256
    unsigned short* wT4 = wT3 + 2048 * 256;           // 768*2048
    unsigned short* mu  = wT4 + 768 * 2048;           // Mc*256
    unsigned short* he  = mu + Mc * LL;               // Mc*2048 (hd aliases he)

    patchify<<<6144, 256, 0, stream>>>(x, patches);

    transpose_k<<<(768 / 32) * (2048 / 32), 256, 0, stream>>>(w_enc1, wT1, 768, 2048);
    transpose_k<<<(2048 / 32) * (512 / 32), 256, 0, stream>>>(w_enc2, wT2, 2048, 512);
    transpose_k<<<(256 / 32) * (2048 / 32), 256, 0, stream>>>(w_dec1, wT3, 256, 2048);
    transpose_k<<<(2048 / 32) * (768 / 32), 256, 0, stream>>>(w_dec2, wT4, 2048, 768);

    for (long m0 = MM - Mc; m0 >= 0; m0 -= Mc) {
        // he = relu(patches[m0:] @ w_enc1 + b_enc1)      Mc x 2048, K=768
        // m97: (Mc/128)*(2048/128) = 2048 blocks, 4 blocks/CU  [R13: 66.4us]
        gemm_m97<1, 0><<<(int)(Mc / 128) * (HID / 128), 256, 0, stream>>>(
            patches + m0 * PP, PP, wT1, b_enc1,
            he, nullptr, nullptr, HID, PP, HID / 128, 0);
        // ml = he @ w_enc2 + b_enc2 -> out1 f32 (transposed) + compact bf16 mu
        gemm_bt128<0, 1><<<(int)(Mc / 128) * (512 / 128), 256, 0, stream>>>(
            he, HID, wT2, b_enc2,
            mu, nullptr, out_ml, 0, HID, 512 / 128, (int)m0);
        // hd = relu(mu @ w_dec1 + b_dec1)                Mc x 2048, K=256
        // m97 (R14 change): 2048 blocks, nt=4 — replaces 256x128 2-phase
        gemm_m97<1, 0><<<(int)(Mc / 128) * (HID / 128), 256, 0, stream>>>(
            mu, LL, wT3, b_dec1,
            he, nullptr, nullptr, HID, LL, HID / 128, 0);
        // recon rows m0.. = sigmoid(hd @ w_dec2 + b_dec2) -> f32 scatter out0
        // m97: (Mc/128)*(768/128) = 768 blocks  [R13: <66us]
        gemm_m97<2, 2><<<(int)(Mc / 128) * (PP / 128), 256, 0, stream>>>(
            he, HID, wT4, b_dec2,
            nullptr, outf, nullptr, 0, HID, PP / 128, (int)m0);
    }
}